// Round 7
// baseline (505.344 us; speedup 1.0000x reference)
//
#include <hip/hip_runtime.h>
#include <hip/hip_bf16.h>

// ---- problem constants ----
constexpr int B   = 8;
constexpr int CIN = 66;
constexpr int H   = 128, W = 128;
constexpr int C1  = 256;
constexpr int NP  = 128;
constexpr int V   = 128;
constexpr int SD  = 128;
constexpr int NRES = 7;
constexpr float RO = 4.0f;

typedef __bf16 bf16x8 __attribute__((ext_vector_type(8)));
typedef float  f32x4  __attribute__((ext_vector_type(4)));
typedef unsigned short u16x8 __attribute__((ext_vector_type(8)));

__device__ inline float bfu2f(unsigned short u) {
    union { unsigned int i; float f; } c; c.i = ((unsigned)u) << 16; return c.f;
}
__device__ inline float b2f(__hip_bfloat16 b) { return __bfloat162float(b); }

// ===================== K0a: pack x -> channel-last bf16 with borders =====================
__global__ __launch_bounds__(256) void k_pack_x(const float* __restrict__ x,
                                                __hip_bfloat16* __restrict__ xp)
{
    const int bi  = blockIdx.x;          // 8*130
    const int b   = bi / 130;
    const int yp  = bi % 130;
    const int tid = threadIdx.x;
    const int y   = yp - 1;
    const bool interior = (y >= 0 && y < H);

    __shared__ float xs[CIN * W];
    if (interior) {
        for (int i = tid; i < CIN * W; i += 256)
            xs[i] = x[((size_t)b * CIN + (i >> 7)) * (H * W) + y * W + (i & 127)];
    }
    __syncthreads();
    __hip_bfloat16* op = xp + ((size_t)b * 130 + yp) * (130 * 72);
    for (int i = tid; i < 130 * 72; i += 256) {
        int xpx = i / 72, c = i - xpx * 72;
        int xx = xpx - 1;
        float v = 0.f;
        if (interior && xx >= 0 && xx < W && c < CIN) v = xs[c * W + xx];
        op[i] = __float2bfloat16(v);
    }
}

// ===================== K0b: ALL weight packs in one launch =====================
// [0,256):    conv3x3 w -> wp2 [3 ky][256 oc][232]
// [256,1280): snake     -> wpk2 [8 l][9 k][128 oc][128 ic]   (linear, for direct-global reads)
// [1280,1536): fw       -> fwb  [256][1024]
// [1536,1792): ppw1[:,256:] -> pw1hb [256][1024]
// [1792,1856): ppw2     -> pw2b [64][256]
// [1856,2112): ppw1[:,:256] transposed -> pw1gb [256 c][256 o]
__global__ __launch_bounds__(256) void k_pack_weights(
    const float* __restrict__ w3, const float* __restrict__ hw,
    const float* __restrict__ rw, const float* __restrict__ fw,
    const float* __restrict__ ppw1, const float* __restrict__ ppw2,
    __hip_bfloat16* __restrict__ wp2, __hip_bfloat16* __restrict__ wpk2,
    __hip_bfloat16* __restrict__ fwb, __hip_bfloat16* __restrict__ pw1hb,
    __hip_bfloat16* __restrict__ pw2b, __hip_bfloat16* __restrict__ pw1gb)
{
    const int bid = blockIdx.x, tid = threadIdx.x;
    if (bid < 256) {
        int oc = bid;
        for (int t = tid; t < 3 * 232; t += 256) {
            int ky = t / 232, s = t - ky * 232;
            float v = 0.f;
            if (s < 216) {
                int kx = s / 72, ic = s - kx * 72;
                if (ic < CIN) v = w3[((size_t)(oc * CIN + ic) * 3 + ky) * 3 + kx];
            }
            wp2[((size_t)ky * 256 + oc) * 232 + s] = __float2bfloat16(v);
        }
    } else if (bid < 1280) {
        int q = bid - 256, l = q >> 7, oc = q & 127;
        for (int t = tid; t < 9 * 128; t += 256) {
            int k = t >> 7, ic = t & 127;
            float v = 0.f;
            if (l == 0) { if (ic < 66) v = hw[((size_t)oc * 66 + ic) * 9 + k]; }
            else v = rw[((((size_t)(l - 1) * 128 + oc) * 128) + ic) * 9 + k];
            wpk2[(((size_t)l * 9 + k) * 128 + oc) * 128 + ic] = __float2bfloat16(v);
        }
    } else if (bid < 1536) {
        int r = bid - 1280;
        for (int c = tid; c < 1024; c += 256)
            fwb[(size_t)r * 1024 + c] = __float2bfloat16(fw[(size_t)r * 1024 + c]);
    } else if (bid < 1792) {
        int r = bid - 1536;
        for (int c = tid; c < 1024; c += 256)
            pw1hb[(size_t)r * 1024 + c] = __float2bfloat16(ppw1[(size_t)r * 1280 + 256 + c]);
    } else if (bid < 1856) {
        int r = bid - 1792;
        for (int c = tid; c < 256; c += 256)
            pw2b[(size_t)r * 256 + c] = __float2bfloat16(ppw2[(size_t)r * 256 + c]);
    } else {
        int o = bid - 1856;
        for (int c = tid; c < 256; c += 256)
            pw1gb[(size_t)c * 256 + o] = __float2bfloat16(ppw1[(size_t)o * 1280 + c]);
    }
}

// ===================== K1: 3x3 conv via implicit-GEMM MFMA (round-3/6 config) =====================
__global__ __launch_bounds__(256, 2) void k_conv3x3_mfma(
    const __hip_bfloat16* __restrict__ xp,   // [8][130][130][72]
    const __hip_bfloat16* __restrict__ wp,   // [3][256][232]
    const float* __restrict__ bias,
    __hip_bfloat16* __restrict__ out)        // [8][128 y][128 x][256 oc]
{
    constexpr int SB = 232;
    __shared__ __hip_bfloat16 ash[9392];
    __shared__ __hip_bfloat16 bsh[128 * SB];

    const int tid = threadIdx.x;
    const int ln  = tid & 63;
    const int wv  = tid >> 6;
    const int wm  = (wv >> 1) * 64;
    const int wn  = (wv & 1) * 64;
    const int l15 = ln & 15;
    const int lhi = ln >> 4;

    const int by  = blockIdx.x;
    const int b   = by >> 7;
    const int y   = by & 127;
    const int ocb = blockIdx.y * 128;

    if (tid < 32) ash[9360 + tid] = __float2bfloat16(0.f);

    f32x4 acc[4][4] = {};

    for (int ky = 0; ky < 3; ++ky) {
        __syncthreads();
        {
            const char* g = (const char*)(xp + ((size_t)b * 130 + y + ky) * 9360);
            for (int off = wv * 1024; off < 18720; off += 4096) {
                int o = off + ln * 16;
                if (o < 18720)
                    __builtin_amdgcn_global_load_lds(
                        (const __attribute__((address_space(1))) void*)(g + o),
                        (__attribute__((address_space(3))) void*)((char*)ash + off),
                        16, 0, 0);
            }
        }
        {
            const char* g = (const char*)(wp + ((size_t)ky * 256 + ocb) * SB);
            for (int off = wv * 1024; off < 59392; off += 4096) {
                int o = off + ln * 16;
                if (o < 59392)
                    __builtin_amdgcn_global_load_lds(
                        (const __attribute__((address_space(1))) void*)(g + o),
                        (__attribute__((address_space(3))) void*)((char*)bsh + off),
                        16, 0, 0);
            }
        }
        __syncthreads();

#pragma unroll
        for (int ks = 0; ks < 7; ++ks) {
            bf16x8 a[4], bq[4];
#pragma unroll
            for (int m = 0; m < 4; ++m) {
                int pos = wm + m * 16 + l15;
                a[m] = *(const bf16x8*)((const char*)ash + pos * 144 + ks * 64 + lhi * 16);
            }
#pragma unroll
            for (int n = 0; n < 4; ++n) {
                int oc = wn + n * 16 + l15;
                bq[n] = *(const bf16x8*)((const char*)bsh + oc * (SB * 2) + ks * 64 + lhi * 16);
            }
#pragma unroll
            for (int m = 0; m < 4; ++m)
#pragma unroll
                for (int n = 0; n < 4; ++n)
                    acc[m][n] = __builtin_amdgcn_mfma_f32_16x16x32_bf16(
                        a[m], bq[n], acc[m][n], 0, 0, 0);
        }
    }

#pragma unroll
    for (int n = 0; n < 4; ++n) {
        int oc = ocb + wn + n * 16 + l15;
        float bb = bias[oc];
#pragma unroll
        for (int m = 0; m < 4; ++m) {
#pragma unroll
            for (int r = 0; r < 4; ++r) {
                int pos = wm + m * 16 + lhi * 4 + r;
                float v = acc[m][n][r] + bb;
                v = v > 0.f ? v : 0.f;
                out[(((size_t)b * 128 + y) * 128 + pos) * 256 + oc] = __float2bfloat16(v);
            }
        }
    }
}

// ===================== K2: 1x1 conv (256 -> 64) MFMA =====================
__global__ __launch_bounds__(256) void k_conv1x1_mfma(
    const __hip_bfloat16* __restrict__ feat1,   // [131072 pos][256]
    const __hip_bfloat16* __restrict__ w2b,     // [64][256]
    const float* __restrict__ b2,
    __hip_bfloat16* __restrict__ feat2)         // [131072 pos][64]
{
    const int tid = threadIdx.x;
    const int ln  = tid & 63;
    const int wv  = tid >> 6;
    const int wm  = wv * 64;
    const int l15 = ln & 15;
    const int lhi = ln >> 4;
    const int pos0 = blockIdx.x * 256;

    __shared__ __hip_bfloat16 wsh[64 * 136];
    for (int i = tid; i < 1024; i += 256) {
        int row = i >> 4, slot = i & 15;
        *(bf16x8*)&wsh[row * 136 + slot * 8] = *(const bf16x8*)(w2b + row * 256 + slot * 8);
    }
    __syncthreads();

    f32x4 acc[4][4] = {};
#pragma unroll
    for (int kk = 0; kk < 8; ++kk) {
        bf16x8 a[4], bq[4];
#pragma unroll
        for (int m = 0; m < 4; ++m)
            a[m] = *(const bf16x8*)(feat1 + (size_t)(pos0 + wm + m * 16 + l15) * 256 + kk * 32 + lhi * 8);
#pragma unroll
        for (int n = 0; n < 4; ++n)
            bq[n] = *(const bf16x8*)&wsh[(n * 16 + l15) * 136 + kk * 32 + lhi * 8];
#pragma unroll
        for (int m = 0; m < 4; ++m)
#pragma unroll
            for (int n = 0; n < 4; ++n)
                acc[m][n] = __builtin_amdgcn_mfma_f32_16x16x32_bf16(a[m], bq[n], acc[m][n], 0, 0, 0);
    }
#pragma unroll
    for (int n = 0; n < 4; ++n) {
        int og = n * 16 + l15;
        float bb = b2[og];
#pragma unroll
        for (int m = 0; m < 4; ++m)
#pragma unroll
            for (int r = 0; r < 4; ++r) {
                int pos = pos0 + wm + m * 16 + lhi * 4 + r;
                feat2[(size_t)pos * 64 + og] = __float2bfloat16(acc[m][n][r] + bb);
            }
    }
}

// ===================== K3: bilinear sample + coords -> X0 [p][v][128] bf16 =====================
__global__ __launch_bounds__(256) void k_sample(
    const __hip_bfloat16* __restrict__ feat2, const float* __restrict__ ipoly,
    const float* __restrict__ cpoly, const int* __restrict__ ind,
    __hip_bfloat16* __restrict__ X0)
{
    const int p = blockIdx.x;
    const int v = threadIdx.x & 127;
    const int half = threadIdx.x >> 7;

    float px = ipoly[(p * V + v) * 2 + 0];
    float py = ipoly[(p * V + v) * 2 + 1];
    float ix = px - 0.5f, iy = py - 0.5f;
    float x0f = floorf(ix), y0f = floorf(iy);
    float wx = ix - x0f, wy = iy - y0f;
    int x0 = (int)x0f, y0 = (int)y0f;

    int   xsv[2] = {x0, x0 + 1}, ysv[2] = {y0, y0 + 1};
    float wxs[2] = {1.f - wx, wx}, wys[2] = {1.f - wy, wy};
    float cw[4]; int cbase[4];
#pragma unroll
    for (int jy = 0; jy < 2; ++jy)
#pragma unroll
        for (int jx = 0; jx < 2; ++jx) {
            int xi = xsv[jx], yi = ysv[jy];
            bool ok = (xi >= 0) && (xi < W) && (yi >= 0) && (yi < H);
            int xc = min(max(xi, 0), W - 1);
            int yc = min(max(yi, 0), H - 1);
            cw[jy * 2 + jx]    = wys[jy] * wxs[jx] * (ok ? 1.f : 0.f);
            cbase[jy * 2 + jx] = yc * W + xc;
        }

    const __hip_bfloat16* fb = feat2 + (size_t)ind[p] * (16384 * 64);
    __hip_bfloat16* xr = X0 + ((size_t)p * V + v) * 128;
#pragma unroll
    for (int ch = 0; ch < 4; ++ch) {
        int chh = half * 4 + ch;
        float s[8];
#pragma unroll
        for (int e = 0; e < 8; ++e) s[e] = 0.f;
#pragma unroll
        for (int j = 0; j < 4; ++j) {
            u16x8 t = *(const u16x8*)(fb + (size_t)cbase[j] * 64 + chh * 8);
#pragma unroll
            for (int e = 0; e < 8; ++e) s[e] += cw[j] * bfu2f(t[e]);
        }
#pragma unroll
        for (int e = 0; e < 8; ++e) xr[chh * 8 + e] = __float2bfloat16(s[e]);
    }
    if (half) {
        xr[64] = __float2bfloat16(cpoly[(p * V + v) * 2 + 0] * RO);
        xr[65] = __float2bfloat16(cpoly[(p * V + v) * 2 + 1] * RO);
        for (int c = 66; c < 128; ++c) xr[c] = __float2bfloat16(0.f);
    }
}

// ===================== K4: MEGA — snake x8 + fused-acc + h1-acc + gmax/gc + h1 + h2 + final =====================
// grid 128 (1 block per poly), 256 thr = 4 waves.
// LDS: state ping-pong 2x[128][136] bf16; h1L [128][264] bf16; gred/gl/gc.
// All weights read direct from global (L2-resident).
__global__ __launch_bounds__(256, 1) void k_mega(
    const __hip_bfloat16* __restrict__ X0,     // [NP][V][128]
    const __hip_bfloat16* __restrict__ wsnk,   // [8][9][128 oc][128 ic]
    const float* __restrict__ hb, const float* __restrict__ hg, const float* __restrict__ hbt,
    const float* __restrict__ rb, const float* __restrict__ rg, const float* __restrict__ rbt,
    const __hip_bfloat16* __restrict__ fwb,    // [256][1024]
    const float* __restrict__ fb,
    const __hip_bfloat16* __restrict__ pw1gb,  // [256 c][256 o]
    const float* __restrict__ pb1,
    const __hip_bfloat16* __restrict__ pw1hb,  // [256][1024]
    const __hip_bfloat16* __restrict__ pw2b,   // [64][256]
    const float* __restrict__ pb2,
    const float* __restrict__ pw3, const float* __restrict__ pb3,
    const float* __restrict__ ipoly,
    float* __restrict__ outp)
{
    __shared__ __hip_bfloat16 s0[128 * 136];
    __shared__ __hip_bfloat16 s1[128 * 136];
    __shared__ __hip_bfloat16 h1L[128 * 264];
    __shared__ float gred[2048];
    __shared__ float gl[256];
    __shared__ float gcv[256];

    const int tid = threadIdx.x;
    const int ln  = tid & 63;
    const int wv  = tid >> 6;
    const int l15 = ln & 15;
    const int lhi = ln >> 4;
    const int wmv = (wv >> 1) * 64;   // v-half (snake M, fused M)
    const int wns = (wv & 1) * 64;    // snake oc-half (64)
    const int wno = (wv & 1) * 128;   // fused/h1 oc-half (128)
    const int p   = blockIdx.x;

    // stage X0 -> s0
    {
        const __hip_bfloat16* xb = X0 + (size_t)p * (V * 128);
        for (int i = tid; i < 2048; i += 256) {
            int r = i >> 4, slot = i & 15;
            *(bf16x8*)&s0[r * 136 + slot * 8] = *(const bf16x8*)(xb + r * 128 + slot * 8);
        }
    }
    __syncthreads();

    f32x4 facc[4][8] = {};
    f32x4 hacc[4][8] = {};
    const int dils[8] = {1, 1, 1, 1, 2, 2, 4, 4};

#pragma unroll 1
    for (int l = 0; l < 8; ++l) {
        __hip_bfloat16* cur  = (l & 1) ? s1 : s0;
        __hip_bfloat16* pong = (l & 1) ? s0 : s1;
        const __hip_bfloat16* wl = wsnk + (size_t)l * (9 * 128 * 128);
        const int dil = dils[l];

        // ---- snake conv: sacc = conv(cur) ----
        f32x4 sacc[4][4] = {};
#pragma unroll 1
        for (int k = 0; k < 9; ++k) {
            const int ofs = (k - 4) * dil + 128;
            const __hip_bfloat16* wk = wl + (size_t)k * (128 * 128);
#pragma unroll
            for (int kc = 0; kc < 4; ++kc) {
                bf16x8 a[4], bq[4];
#pragma unroll
                for (int m = 0; m < 4; ++m) {
                    int row = (wmv + m * 16 + l15 + ofs) & 127;
                    a[m] = *(const bf16x8*)&cur[row * 136 + kc * 32 + lhi * 8];
                }
#pragma unroll
                for (int n = 0; n < 4; ++n)
                    bq[n] = *(const bf16x8*)(wk + (size_t)(wns + n * 16 + l15) * 128 + kc * 32 + lhi * 8);
#pragma unroll
                for (int m = 0; m < 4; ++m)
#pragma unroll
                    for (int n = 0; n < 4; ++n)
                        sacc[m][n] = __builtin_amdgcn_mfma_f32_16x16x32_bf16(a[m], bq[n], sacc[m][n], 0, 0, 0);
            }
        }

        // ---- epilogue: bn(relu(.)) [+ residual] -> pong ----
        const float* bbp = l ? (rb  + (l - 1) * 128) : hb;
        const float* ggp = l ? (rg  + (l - 1) * 128) : hg;
        const float* btp = l ? (rbt + (l - 1) * 128) : hbt;
#pragma unroll
        for (int n = 0; n < 4; ++n) {
            int oc = wns + n * 16 + l15;
            float bb = bbp[oc], gg = ggp[oc], bt = btp[oc];
#pragma unroll
            for (int m = 0; m < 4; ++m)
#pragma unroll
                for (int r = 0; r < 4; ++r) {
                    int pos = wmv + m * 16 + lhi * 4 + r;
                    float v = sacc[m][n][r] + bb;
                    v = v > 0.f ? v : 0.f;
                    v = v * gg + bt;
                    if (l) v += b2f(cur[pos * 136 + oc]);
                    pong[pos * 136 + oc] = __float2bfloat16(v);
                }
        }
        __syncthreads();

        // ---- fused-acc and h1-acc over this state chunk (K=128) ----
#pragma unroll
        for (int kc = 0; kc < 4; ++kc) {
            bf16x8 a2[4], bqf[8], bqh[8];
#pragma unroll
            for (int m = 0; m < 4; ++m)
                a2[m] = *(const bf16x8*)&pong[(wmv + m * 16 + l15) * 136 + kc * 32 + lhi * 8];
#pragma unroll
            for (int n = 0; n < 8; ++n) {
                size_t row = (size_t)(wno + n * 16 + l15);
                bqf[n] = *(const bf16x8*)(fwb   + row * 1024 + l * 128 + kc * 32 + lhi * 8);
                bqh[n] = *(const bf16x8*)(pw1hb + row * 1024 + l * 128 + kc * 32 + lhi * 8);
            }
#pragma unroll
            for (int m = 0; m < 4; ++m)
#pragma unroll
                for (int n = 0; n < 8; ++n) {
                    facc[m][n] = __builtin_amdgcn_mfma_f32_16x16x32_bf16(a2[m], bqf[n], facc[m][n], 0, 0, 0);
                    hacc[m][n] = __builtin_amdgcn_mfma_f32_16x16x32_bf16(a2[m], bqh[n], hacc[m][n], 0, 0, 0);
                }
        }
        // no barrier needed: next layer reads pong (no writes to it until its own epilogue)
    }

    // ---- gmax: per-lane partial max over v, reduce via LDS ----
#pragma unroll
    for (int n = 0; n < 8; ++n) {
        f32x4 t = facc[0][n];
        float mm = fmaxf(fmaxf(t[0], t[1]), fmaxf(t[2], t[3]));
#pragma unroll
        for (int m = 1; m < 4; ++m) {
            f32x4 u = facc[m][n];
            mm = fmaxf(mm, fmaxf(fmaxf(u[0], u[1]), fmaxf(u[2], u[3])));
        }
        gred[(wv >> 1) * 1024 + lhi * 256 + wno + n * 16 + l15] = mm;
    }
    __syncthreads();
    {
        int o = tid;
        float g = gred[o];
#pragma unroll
        for (int q = 1; q < 8; ++q)
            g = fmaxf(g, gred[(q >> 2) * 1024 + (q & 3) * 256 + o]);
        gl[o] = g + fb[o];
    }
    __syncthreads();
    // ---- gc[o] = pb1[o] + sum_c pw1g[o][c] * gl[c]  (pw1gb is [c][o]) ----
    {
        int o = tid;
        float a = pb1[o];
        for (int c = 0; c < 256; ++c)
            a += b2f(pw1gb[(size_t)c * 256 + o]) * gl[c];
        gcv[o] = a;
    }
    __syncthreads();

    // ---- h1 = relu(hacc + gc) -> h1L [v][264] ----
#pragma unroll
    for (int n = 0; n < 8; ++n) {
        int oc = wno + n * 16 + l15;
        float gco = gcv[oc];
#pragma unroll
        for (int m = 0; m < 4; ++m)
#pragma unroll
            for (int r = 0; r < 4; ++r) {
                int v = wmv + m * 16 + lhi * 4 + r;
                float hv = hacc[m][n][r] + gco;
                hv = hv > 0.f ? hv : 0.f;
                h1L[v * 264 + oc] = __float2bfloat16(hv);
            }
    }
    __syncthreads();

    // ---- h2 = relu(pw2 @ h1 + pb2): out [128 v][64 oc2] ----
    {
        const int wm2 = (wv >> 1) * 64;
        const int wn2 = (wv & 1) * 32;
        f32x4 acc2[4][2] = {};
#pragma unroll
        for (int kk = 0; kk < 8; ++kk) {
            bf16x8 a3[4], bq3[2];
#pragma unroll
            for (int m = 0; m < 4; ++m)
                a3[m] = *(const bf16x8*)&h1L[(wm2 + m * 16 + l15) * 264 + kk * 32 + lhi * 8];
#pragma unroll
            for (int n = 0; n < 2; ++n)
                bq3[n] = *(const bf16x8*)(pw2b + (size_t)(wn2 + n * 16 + l15) * 256 + kk * 32 + lhi * 8);
#pragma unroll
            for (int m = 0; m < 4; ++m)
#pragma unroll
                for (int n = 0; n < 2; ++n)
                    acc2[m][n] = __builtin_amdgcn_mfma_f32_16x16x32_bf16(a3[m], bq3[n], acc2[m][n], 0, 0, 0);
        }
        __hip_bfloat16* h2L = s0;   // reuse [128 v][72]
#pragma unroll
        for (int n = 0; n < 2; ++n) {
            int oc2 = wn2 + n * 16 + l15;
            float bb = pb2[oc2];
#pragma unroll
            for (int m = 0; m < 4; ++m)
#pragma unroll
                for (int r = 0; r < 4; ++r) {
                    int v = wm2 + m * 16 + lhi * 4 + r;
                    float hv = acc2[m][n][r] + bb;
                    hv = hv > 0.f ? hv : 0.f;
                    h2L[v * 72 + oc2] = __float2bfloat16(hv);
                }
        }
    }
    __syncthreads();

    // ---- final: out = ipoly*RO + pw3 @ h2 + pb3 ----
    if (tid < 128) {
        int v = tid;
        const __hip_bfloat16* h2L = s0;
        float a0 = pb3[0], a1 = pb3[1];
        for (int c = 0; c < 64; ++c) {
            float hv = b2f(h2L[v * 72 + c]);
            a0 += pw3[c] * hv;
            a1 += pw3[64 + c] * hv;
        }
        int idx = (p * V + v) * 2;
        outp[idx]     = ipoly[idx] * RO + a0;
        outp[idx + 1] = ipoly[idx + 1] * RO + a1;
    }
}

// ===================== host =====================
extern "C" void kernel_launch(void* const* d_in, const int* in_sizes, int n_in,
                              void* d_out, int out_size, void* d_ws, size_t ws_size,
                              hipStream_t stream)
{
    const float* cnn   = (const float*)d_in[0];
    const float* ipoly = (const float*)d_in[1];
    const float* cpoly = (const float*)d_in[2];
    const int*   ind   = (const int*)d_in[3];
    const float* pw1c  = (const float*)d_in[4];
    const float* pb1c  = (const float*)d_in[5];
    const float* pw2c  = (const float*)d_in[6];
    const float* pb2c  = (const float*)d_in[7];
    const float* hw    = (const float*)d_in[8];
    const float* hb    = (const float*)d_in[9];
    const float* hg    = (const float*)d_in[10];
    const float* hbt   = (const float*)d_in[11];
    const float* rw    = (const float*)d_in[12];
    const float* rb    = (const float*)d_in[13];
    const float* rg    = (const float*)d_in[14];
    const float* rbt   = (const float*)d_in[15];
    const float* fw    = (const float*)d_in[16];
    const float* fb    = (const float*)d_in[17];
    const float* ppw1  = (const float*)d_in[18];
    const float* ppb1  = (const float*)d_in[19];
    const float* ppw2  = (const float*)d_in[20];
    const float* ppb2  = (const float*)d_in[21];
    const float* ppw3  = (const float*)d_in[22];
    const float* ppb3  = (const float*)d_in[23];
    float* outp = (float*)d_out;

    char* ws = (char*)d_ws;
    // layout:
    //  [0,64M): feat1 [131072][256] bf16
    //  [64M..): xp (19.5MB) -> aliased later by feat2 [131072][64] bf16 (16MB)
    //  tail: wp2, wpk2, fwb, pw1hb, pw2b, pw1gb, X0
    __hip_bfloat16* feat1  = (__hip_bfloat16*)(ws);
    __hip_bfloat16* xp     = (__hip_bfloat16*)(ws + 67108864);
    __hip_bfloat16* feat2  = (__hip_bfloat16*)(ws + 67108864);
    __hip_bfloat16* wp2    = (__hip_bfloat16*)(ws + 86577664);
    __hip_bfloat16* wpk2   = (__hip_bfloat16*)(ws + 86934016);
    __hip_bfloat16* fwb    = (__hip_bfloat16*)(ws + 89293312);
    __hip_bfloat16* pw1hb  = (__hip_bfloat16*)(ws + 89817600);
    __hip_bfloat16* pw2b   = (__hip_bfloat16*)(ws + 90341888);
    __hip_bfloat16* pw1gb  = (__hip_bfloat16*)(ws + 90374656);
    __hip_bfloat16* X0     = (__hip_bfloat16*)(ws + 90505728);

    // 0) packs (2 launches)
    k_pack_x<<<dim3(8 * 130), 256, 0, stream>>>(cnn, xp);
    k_pack_weights<<<dim3(2112), 256, 0, stream>>>(pw1c, hw, rw, fw, ppw1, ppw2,
                                                   wp2, wpk2, fwb, pw1hb, pw2b, pw1gb);

    // 1) 3x3 conv + relu -> feat1 (channel-last bf16)
    k_conv3x3_mfma<<<dim3(1024, 2), 256, 0, stream>>>(xp, wp2, pb1c, feat1);
    // 2) 1x1 conv -> feat2 (channel-last bf16)
    k_conv1x1_mfma<<<dim3(512), 256, 0, stream>>>(feat1, pw2b, pb2c, feat2);
    // 3) bilinear sample + coords -> X0 [p][v][128] bf16
    k_sample<<<dim3(NP), 256, 0, stream>>>(feat2, ipoly, cpoly, ind, X0);
    // 4) everything else in ONE kernel
    k_mega<<<dim3(NP), 256, 0, stream>>>(X0, wpk2, hb, hg, hbt, rb, rg, rbt,
                                         fwb, fb, pw1gb, ppb1, pw1hb, pw2b, ppb2,
                                         ppw3, ppb3, ipoly, outp);
}